// Round 4
// baseline (1249.557 us; speedup 1.0000x reference)
//
#include <hip/hip_runtime.h>
#include <math.h>

#define BB 128
#define TT 1024
#define DD 128
#define HH 64
#define G3 192   // 3*H
#define KK 32

// ---------------------------------------------------------------------------
// Kernel 1: xproj[B*T,192] = X[B*T,128] @ Wk[128,192] + b0
// Tiled GEMM: block = 256 thr, tile 64 rows x 64 cols (grid.y = 3 col groups),
// 4x4 microtile per thread, padded LDS.
// ---------------------------------------------------------------------------
__global__ __launch_bounds__(256, 2) void xproj_kernel(const float* __restrict__ X,
                                                       const float* __restrict__ Wk,
                                                       const float* __restrict__ gbias,
                                                       float* __restrict__ xp) {
    __shared__ float Xs[64 * 132];             // 64 rows x 128 k, stride 132 (pad)
    __shared__ float Ws[128 * 68];             // 128 k x 64 cols, stride 68 (pad)
    const int tid = threadIdx.x;
    const int row0 = blockIdx.x * 64;
    const int cg = blockIdx.y;                 // col group 0..2
#pragma unroll
    for (int it = 0; it < 8; ++it) {
        int idx = it * 1024 + tid * 4;
        int r = idx >> 7, c = idx & 127;
        float4 v = *(const float4*)&X[((size_t)(row0 + r)) * DD + c];
        *(float4*)&Xs[r * 132 + c] = v;
    }
#pragma unroll
    for (int it = 0; it < 8; ++it) {
        int idx = it * 1024 + tid * 4;
        int k = idx >> 6, c = idx & 63;
        float4 v = *(const float4*)&Wk[(size_t)k * G3 + cg * 64 + c];
        *(float4*)&Ws[k * 68 + c] = v;
    }
    __syncthreads();
    const int tr = tid >> 4, tc = tid & 15;    // 16x16 thread grid
    const int r0 = tr * 4, c0 = tc * 4;
    float acc[4][4];
#pragma unroll
    for (int r = 0; r < 4; ++r)
#pragma unroll
        for (int c = 0; c < 4; ++c) acc[r][c] = 0.f;
#pragma unroll 4
    for (int k = 0; k < DD; k += 4) {
        float a[4][4];
#pragma unroll
        for (int r = 0; r < 4; ++r) {
            float4 t = *(const float4*)&Xs[(r0 + r) * 132 + k];
            a[r][0] = t.x; a[r][1] = t.y; a[r][2] = t.z; a[r][3] = t.w;
        }
#pragma unroll
        for (int kk = 0; kk < 4; ++kk) {
            float4 b = *(const float4*)&Ws[(k + kk) * 68 + c0];
#pragma unroll
            for (int r = 0; r < 4; ++r) {
                acc[r][0] += a[r][kk] * b.x;
                acc[r][1] += a[r][kk] * b.y;
                acc[r][2] += a[r][kk] * b.z;
                acc[r][3] += a[r][kk] * b.w;
            }
        }
    }
    float4 bias = *(const float4*)&gbias[cg * 64 + c0];
#pragma unroll
    for (int r = 0; r < 4; ++r) {
        float4 o;
        o.x = acc[r][0] + bias.x; o.y = acc[r][1] + bias.y;
        o.z = acc[r][2] + bias.z; o.w = acc[r][3] + bias.w;
        *(float4*)&xp[((size_t)(row0 + r0 + r)) * G3 + cg * 64 + c0] = o;
    }
}

// ---------------------------------------------------------------------------
// Kernel 2: seq_len + chain copy
// ---------------------------------------------------------------------------
__global__ __launch_bounds__(256) void seqlen_kernel(const int* __restrict__ mask,
                                                     const float* __restrict__ chain,
                                                     float* __restrict__ out_seqlen,
                                                     float* __restrict__ out_chain,
                                                     int* __restrict__ ws_seqlen) {
    const int b = blockIdx.x;
    const int tid = threadIdx.x;
    int s = 0;
    for (int t = tid; t < TT; t += 256) s += mask[b * TT + t];
#pragma unroll
    for (int off = 32; off >= 1; off >>= 1) s += __shfl_down(s, off, 64);
    __shared__ int red[4];
    if ((tid & 63) == 0) red[tid >> 6] = s;
    __syncthreads();
    if (tid == 0) {
        int tot = red[0] + red[1] + red[2] + red[3];
        out_seqlen[b] = (float)tot;
        ws_seqlen[b] = tot;
    }
    if (b == 0) {
        for (int i = tid; i < KK * KK; i += 256) out_chain[i] = chain[i];
    }
}

// ---------------------------------------------------------------------------
// Kernel 3: GRU scan. ONE WAVE per batch. amdgpu_waves_per_eu(1,1) lifts the
// VGPR budget to 512 so all 192 weight floats stay register-resident
// (the RA was targeting 4 waves/EU = 128 VGPRs and spilling to scratch).
// h broadcast with v_readlane. No LDS, no barriers.
// ---------------------------------------------------------------------------
#define BCAST(v, l) __int_as_float(__builtin_amdgcn_readlane(__float_as_int(v), (l)))

__global__ __launch_bounds__(64)
__attribute__((amdgpu_waves_per_eu(1, 1)))
void gru_kernel(const float* __restrict__ xp,
                const float* __restrict__ Wr,
                const float* __restrict__ gbias,
                const int* __restrict__ mask,
                float* __restrict__ hidden) {
    const int b = blockIdx.x;
    const int j = threadIdx.x;                 // 0..63
    float wz[HH], wrr[HH], wh[HH];
#define LW(i) wz[(i)] = Wr[(i) * G3 + j]; \
              wrr[(i)] = Wr[(i) * G3 + HH + j]; \
              wh[(i)] = Wr[(i) * G3 + 2 * HH + j];
#define LW4(i)  LW(i) LW((i)+1) LW((i)+2) LW((i)+3)
#define LW16(i) LW4(i) LW4((i)+4) LW4((i)+8) LW4((i)+12)
    LW16(0) LW16(16) LW16(32) LW16(48)
    const float bz = gbias[G3 + j];
    const float br = gbias[G3 + HH + j];
    const float bh = gbias[G3 + 2 * HH + j];
    float h = 0.f;
    const float* xpb = xp + (size_t)b * TT * G3;
    const int bTT = b * TT;
    float xz = xpb[j], xr = xpb[HH + j], xh = xpb[2 * HH + j];
    int m = mask[bTT];
    for (int t = 0; t < TT; ++t) {
        const int tn = (t + 1 < TT) ? t + 1 : TT - 1;
        const float* xn = xpb + (size_t)tn * G3;
        float nxz = xn[j], nxr = xn[HH + j], nxh = xn[2 * HH + j];
        int nm = mask[bTT + tn];
        // 6 accumulator chains for ILP; literal-index FMA over 64 h lanes
        float az0 = bz, ar0 = br, ah0 = bh;
        float az1 = 0.f, ar1 = 0.f, ah1 = 0.f;
#define ST(i, A, B, C) { float hi_ = BCAST(h, (i)); A += hi_ * wz[(i)]; B += hi_ * wrr[(i)]; C += hi_ * wh[(i)]; }
#define ST2(i)  ST(i, az0, ar0, ah0) ST((i)+1, az1, ar1, ah1)
#define ST8(i)  ST2(i) ST2((i)+2) ST2((i)+4) ST2((i)+6)
#define ST32(i) ST8(i) ST8((i)+8) ST8((i)+16) ST8((i)+24)
        ST32(0) ST32(32)
        float az = az0 + az1, ar = ar0 + ar1, ah = ah0 + ah1;
        float z = 1.f / (1.f + __expf(-(xz + az)));
        float r = 1.f / (1.f + __expf(-(xr + ar)));
        float y = xh + r * ah;
        float hh = 1.f - 2.f / (1.f + __expf(2.f * y));   // tanh(y)
        float hn = z * h + (1.f - z) * hh;
        hn = (m != 0) ? hn : h;
        hidden[((size_t)(bTT + t)) * HH + j] = hn;
        h = hn;
        xz = nxz; xr = nxr; xh = nxh; m = nm;
    }
}

// ---------------------------------------------------------------------------
// Kernel 4: potentials[row,k] = hidden[row,:]@Dk[:,k] + db[k] (+ boundaries)
// ---------------------------------------------------------------------------
#define PR 8
__global__ __launch_bounds__(256) void pot_kernel(const float* __restrict__ hidden,
                                                  const float* __restrict__ Dk,
                                                  const float* __restrict__ db,
                                                  const float* __restrict__ lb,
                                                  const float* __restrict__ rb,
                                                  const int* __restrict__ slen,
                                                  float* __restrict__ pot) {
    __shared__ float Hs[PR * HH];
    __shared__ float Dks[HH * KK];
    const int tid = threadIdx.x;
    const int k = tid & (KK - 1);
    const int rl = tid >> 5;                   // 0..7
    const size_t row0 = (size_t)blockIdx.x * PR;
    for (int idx = tid; idx < PR * HH; idx += 256) Hs[idx] = hidden[row0 * HH + idx];
    for (int idx = tid; idx < HH * KK; idx += 256) Dks[idx] = Dk[idx];
    __syncthreads();
    float acc = db[k];
#pragma unroll
    for (int i = 0; i < HH; i += 4) {
        float4 hv = *(const float4*)&Hs[rl * HH + i];
        acc += hv.x * Dks[i * KK + k] + hv.y * Dks[(i + 1) * KK + k]
             + hv.z * Dks[(i + 2) * KK + k] + hv.w * Dks[(i + 3) * KK + k];
    }
    const size_t row = row0 + rl;
    const int t = (int)(row & (TT - 1));
    const int bb = (int)(row >> 10);
    if (t == 0) acc += lb[k];
    if (t == slen[bb] - 1) acc += rb[k];
    pot[row * KK + k] = acc;
}

// ---------------------------------------------------------------------------
// Kernel 5: Viterbi. Forward on wave 0: ds_bpermute broadcasts + depth-4
// compare-select tree argmax; bp uint8 in LDS; chunked parallel backtrack.
// ---------------------------------------------------------------------------
__global__ __launch_bounds__(256) void viterbi_kernel(const float* __restrict__ pot,
                                                      const float* __restrict__ chain,
                                                      float* __restrict__ decoded) {
    const int b = blockIdx.x;
    const int tid = threadIdx.x;
    __shared__ unsigned char bp[(TT - 1) * KK];        // 32736 B
    __shared__ unsigned char table[32 * 32 * KK];      // 32 chunks x 32 pos x 32 cand
    __shared__ int ent[32];
    __shared__ int last_tag_s;
    const float* pb = pot + (size_t)b * TT * KK;

    if (tid < 64) {
        const int k = tid & 31;
        const int hf = tid >> 5;                       // half: k_from in [16h,16h+16)
        float ccol[16];
        int addr[16];
#pragma unroll
        for (int m = 0; m < 16; ++m) {
            ccol[m] = chain[(hf * 16 + m) * KK + k];
            addr[m] = (hf * 16 + m) * 4;
        }
        const int addrx = (tid ^ 32) * 4;
        float s = pb[k];
        float pv_next = pb[KK + k];
        for (int t = 1; t < TT; ++t) {
            float pv = pv_next;
            pv_next = pb[(size_t)(t + 1) * KK + k];    // t+1==TT reads into slen area of d_out: safe
            const int si = __float_as_int(s);
            float c[16];
#pragma unroll
            for (int m = 0; m < 16; ++m)
                c[m] = __int_as_float(__builtin_amdgcn_ds_bpermute(addr[m], si)) + ccol[m];
            float v1[8]; int i1[8];
#pragma unroll
            for (int p = 0; p < 8; ++p) {
                bool tk = c[2 * p + 1] > c[2 * p];
                v1[p] = tk ? c[2 * p + 1] : c[2 * p];
                i1[p] = hf * 16 + (tk ? 2 * p + 1 : 2 * p);
            }
            float v2[4]; int i2[4];
#pragma unroll
            for (int p = 0; p < 4; ++p) {
                bool tk = v1[2 * p + 1] > v1[2 * p];
                v2[p] = tk ? v1[2 * p + 1] : v1[2 * p];
                i2[p] = tk ? i1[2 * p + 1] : i1[2 * p];
            }
            float v3[2]; int i3[2];
#pragma unroll
            for (int p = 0; p < 2; ++p) {
                bool tk = v2[2 * p + 1] > v2[2 * p];
                v3[p] = tk ? v2[2 * p + 1] : v2[2 * p];
                i3[p] = tk ? i2[2 * p + 1] : i2[2 * p];
            }
            bool tk = v3[1] > v3[0];
            float bv = tk ? v3[1] : v3[0];
            int bi = tk ? i3[1] : i3[0];
            float ov = __int_as_float(__builtin_amdgcn_ds_bpermute(addrx, __float_as_int(bv)));
            int   oi = __builtin_amdgcn_ds_bpermute(addrx, bi);
            bool take = (ov > bv) || (ov == bv && oi < bi);
            if (take) { bv = ov; bi = oi; }
            if (tid < 32) bp[(t - 1) * KK + k] = (unsigned char)bi;
            s = bv + pv;
        }
        float bv = s; int bi = k;
#pragma unroll
        for (int d = 16; d >= 1; d >>= 1) {
            float ov = __shfl_xor(bv, d, 64);
            int   oi = __shfl_xor(bi, d, 64);
            bool take = (ov > bv) || (ov == bv && oi < bi);
            if (take) { bv = ov; bi = oi; }
        }
        if (tid == 0) last_tag_s = bi;
    }
    __syncthreads();
    {
        const int k = tid & 31;
        const int cs = tid >> 5;                       // 0..7
        for (int cc = 0; cc < 4; ++cc) {
            const int c = cs * 4 + cc;
            int tag = k;
            for (int l = 31; l >= 0; --l) {
                const int t = c * 32 + l;
                if (t < TT - 1) tag = bp[t * KK + tag];
                table[(c * 32 + l) * KK + k] = (unsigned char)tag;
            }
        }
    }
    __syncthreads();
    if (tid == 0) {
        int e = last_tag_s;
        ent[31] = e;
        for (int c = 30; c >= 0; --c) { e = table[(c + 1) * 32 * KK + e]; ent[c] = e; }
    }
    __syncthreads();
    for (int t = tid; t < TT; t += 256) {
        const int c = t >> 5, l = t & 31;
        decoded[(size_t)b * TT + t] = (float)table[(c * 32 + l) * KK + ent[c]];
    }
}

// ---------------------------------------------------------------------------
extern "C" void kernel_launch(void* const* d_in, const int* in_sizes, int n_in,
                              void* d_out, int out_size, void* d_ws, size_t ws_size,
                              hipStream_t stream) {
    const float* X     = (const float*)d_in[0];
    const int*   mask  = (const int*)d_in[1];
    const float* Wk    = (const float*)d_in[2];   // [128,192]
    const float* Wr    = (const float*)d_in[3];   // [64,192]
    const float* gb    = (const float*)d_in[4];   // [2,192]
    const float* Dk    = (const float*)d_in[5];   // [64,32]
    const float* db    = (const float*)d_in[6];   // [32]
    const float* chain = (const float*)d_in[7];   // [32,32]
    const float* lb    = (const float*)d_in[8];
    const float* rb    = (const float*)d_in[9];

    float* out = (float*)d_out;
    float* out_dec  = out;                                   // [B,T]
    float* out_pot  = out + (size_t)BB * TT;                 // [B,T,K]
    float* out_slen = out + (size_t)BB * TT + (size_t)BB * TT * KK;        // [B]
    float* out_chn  = out_slen + BB;                         // [K,K]

    float* ws = (float*)d_ws;
    float* xp     = ws;                                      // [B*T,192]
    float* hidden = ws + (size_t)BB * TT * G3;               // [B*T,64]
    int*   slen_i = (int*)(hidden + (size_t)BB * TT * HH);   // [B]

    xproj_kernel<<<dim3((BB * TT) / 64, 3), dim3(256), 0, stream>>>(X, Wk, gb, xp);
    seqlen_kernel<<<dim3(BB), dim3(256), 0, stream>>>(mask, chain, out_slen, out_chn, slen_i);
    gru_kernel<<<dim3(BB), dim3(64), 0, stream>>>(xp, Wr, gb, mask, hidden);
    pot_kernel<<<dim3((BB * TT) / PR), dim3(256), 0, stream>>>(hidden, Dk, db, lb, rb, slen_i, out_pot);
    viterbi_kernel<<<dim3(BB), dim3(256), 0, stream>>>(out_pot, chain, out_dec);
}

// Round 5
// 1221.333 us; speedup vs baseline: 1.0231x; 1.0231x over previous
//
#include <hip/hip_runtime.h>
#include <math.h>

#define BB 128
#define TT 1024
#define DD 128
#define HH 64
#define G3 192   // 3*H
#define KK 32

// ---------------------------------------------------------------------------
// Kernel 1: xproj[B*T,192] = X[B*T,128] @ Wk[128,192] + b0
// ---------------------------------------------------------------------------
__global__ __launch_bounds__(256, 2) void xproj_kernel(const float* __restrict__ X,
                                                       const float* __restrict__ Wk,
                                                       const float* __restrict__ gbias,
                                                       float* __restrict__ xp) {
    __shared__ float Xs[64 * 132];             // 64 rows x 128 k, stride 132 (pad)
    __shared__ float Ws[128 * 68];             // 128 k x 64 cols, stride 68 (pad)
    const int tid = threadIdx.x;
    const int row0 = blockIdx.x * 64;
    const int cg = blockIdx.y;                 // col group 0..2
#pragma unroll
    for (int it = 0; it < 8; ++it) {
        int idx = it * 1024 + tid * 4;
        int r = idx >> 7, c = idx & 127;
        float4 v = *(const float4*)&X[((size_t)(row0 + r)) * DD + c];
        *(float4*)&Xs[r * 132 + c] = v;
    }
#pragma unroll
    for (int it = 0; it < 8; ++it) {
        int idx = it * 1024 + tid * 4;
        int k = idx >> 6, c = idx & 63;
        float4 v = *(const float4*)&Wk[(size_t)k * G3 + cg * 64 + c];
        *(float4*)&Ws[k * 68 + c] = v;
    }
    __syncthreads();
    const int tr = tid >> 4, tc = tid & 15;    // 16x16 thread grid
    const int r0 = tr * 4, c0 = tc * 4;
    float acc[4][4];
#pragma unroll
    for (int r = 0; r < 4; ++r)
#pragma unroll
        for (int c = 0; c < 4; ++c) acc[r][c] = 0.f;
#pragma unroll 4
    for (int k = 0; k < DD; k += 4) {
        float a[4][4];
#pragma unroll
        for (int r = 0; r < 4; ++r) {
            float4 t = *(const float4*)&Xs[(r0 + r) * 132 + k];
            a[r][0] = t.x; a[r][1] = t.y; a[r][2] = t.z; a[r][3] = t.w;
        }
#pragma unroll
        for (int kk = 0; kk < 4; ++kk) {
            float4 b = *(const float4*)&Ws[(k + kk) * 68 + c0];
#pragma unroll
            for (int r = 0; r < 4; ++r) {
                acc[r][0] += a[r][kk] * b.x;
                acc[r][1] += a[r][kk] * b.y;
                acc[r][2] += a[r][kk] * b.z;
                acc[r][3] += a[r][kk] * b.w;
            }
        }
    }
    float4 bias = *(const float4*)&gbias[cg * 64 + c0];
#pragma unroll
    for (int r = 0; r < 4; ++r) {
        float4 o;
        o.x = acc[r][0] + bias.x; o.y = acc[r][1] + bias.y;
        o.z = acc[r][2] + bias.z; o.w = acc[r][3] + bias.w;
        *(float4*)&xp[((size_t)(row0 + r0 + r)) * G3 + cg * 64 + c0] = o;
    }
}

// ---------------------------------------------------------------------------
// Kernel 2: seq_len + chain copy
// ---------------------------------------------------------------------------
__global__ __launch_bounds__(256) void seqlen_kernel(const int* __restrict__ mask,
                                                     const float* __restrict__ chain,
                                                     float* __restrict__ out_seqlen,
                                                     float* __restrict__ out_chain,
                                                     int* __restrict__ ws_seqlen) {
    const int b = blockIdx.x;
    const int tid = threadIdx.x;
    int s = 0;
    for (int t = tid; t < TT; t += 256) s += mask[b * TT + t];
#pragma unroll
    for (int off = 32; off >= 1; off >>= 1) s += __shfl_down(s, off, 64);
    __shared__ int red[4];
    if ((tid & 63) == 0) red[tid >> 6] = s;
    __syncthreads();
    if (tid == 0) {
        int tot = red[0] + red[1] + red[2] + red[3];
        out_seqlen[b] = (float)tot;
        ws_seqlen[b] = tot;
    }
    if (b == 0) {
        for (int i = tid; i < KK * KK; i += 256) out_chain[i] = chain[i];
    }
}

// ---------------------------------------------------------------------------
// Kernel 3: GRU scan — 3-wave gate split. Wave w (0=z,1=r,2=h) owns gate w:
// lane j holds Wr[:, w*64+j] in 64 VGPRs (fits ANY occupancy budget -> no
// spills, unlike the 192-VGPR single-wave version the RA refused to keep
// resident). Gates meet in a double-buffered LDS strip; ONE barrier/step.
// Every wave keeps a redundant distributed copy of h (lane j holds h_j).
// ---------------------------------------------------------------------------
#define BCAST(v, l) __int_as_float(__builtin_amdgcn_readlane(__float_as_int(v), (l)))

__global__ __launch_bounds__(192)
void gru_kernel(const float* __restrict__ xp,
                const float* __restrict__ Wr,
                const float* __restrict__ gbias,
                const int* __restrict__ mask,
                float* __restrict__ hidden) {
    const int b = blockIdx.x;
    const int tid = threadIdx.x;
    const int w = tid >> 6;                    // gate: 0=z, 1=r, 2=h-candidate
    const int j = tid & 63;
    __shared__ float gbuf[2][4 * HH];          // z | r | rh | xh, double-buffered
    float wg[HH];
#define LWG(i)  wg[(i)] = Wr[(i) * G3 + w * HH + j];
#define LWG4(i)  LWG(i) LWG((i)+1) LWG((i)+2) LWG((i)+3)
#define LWG16(i) LWG4(i) LWG4((i)+4) LWG4((i)+8) LWG4((i)+12)
    LWG16(0) LWG16(16) LWG16(32) LWG16(48)
    const float bw = gbias[G3 + w * HH + j];   // recurrent bias for this gate
    float h = 0.f;                             // lane j holds h_j (per-wave copy)
    const float* xpb = xp + (size_t)b * TT * G3 + w * HH + j;
    const int bTT = b * TT;
    float xv = xpb[0];
    int m = mask[bTT];
    for (int t = 0; t < TT; ++t) {
        const int tn = (t + 1 < TT) ? t + 1 : TT - 1;
        float nxv = xpb[(size_t)tn * G3];
        int nm = mask[bTT + tn];
        // recurrent matvec for this gate: 64 readlane-broadcasts + 64 fmac
        float a0 = bw, a1 = 0.f;
#define GST(i, A) { float hi_ = BCAST(h, (i)); A += hi_ * wg[(i)]; }
#define GST2(i)  GST(i, a0) GST((i)+1, a1)
#define GST8(i)  GST2(i) GST2((i)+2) GST2((i)+4) GST2((i)+6)
#define GST32(i) GST8(i) GST8((i)+8) GST8((i)+16) GST8((i)+24)
        GST32(0) GST32(32)
        float a = a0 + a1;
        float g = (w == 2) ? a : 1.f / (1.f + __expf(-(xv + a)));
        const int p = t & 1;
        gbuf[p][w * HH + j] = g;
        if (w == 2) gbuf[p][3 * HH + j] = xv;  // xh
        __syncthreads();
        float z  = gbuf[p][j];
        float r  = gbuf[p][HH + j];
        float rh = gbuf[p][2 * HH + j];
        float xh = gbuf[p][3 * HH + j];
        float y = xh + r * rh;
        float hh = 1.f - 2.f / (1.f + __expf(2.f * y));   // tanh(y)
        float hn = z * h + (1.f - z) * hh;
        hn = (m != 0) ? hn : h;
        if (w == 0) hidden[((size_t)(bTT + t)) * HH + j] = hn;
        h = hn;
        xv = nxv; m = nm;
    }
}

// ---------------------------------------------------------------------------
// Kernel 4: potentials[row,k] = hidden[row,:]@Dk[:,k] + db[k] (+ boundaries)
// ---------------------------------------------------------------------------
#define PR 8
__global__ __launch_bounds__(256) void pot_kernel(const float* __restrict__ hidden,
                                                  const float* __restrict__ Dk,
                                                  const float* __restrict__ db,
                                                  const float* __restrict__ lb,
                                                  const float* __restrict__ rb,
                                                  const int* __restrict__ slen,
                                                  float* __restrict__ pot) {
    __shared__ float Hs[PR * HH];
    __shared__ float Dks[HH * KK];
    const int tid = threadIdx.x;
    const int k = tid & (KK - 1);
    const int rl = tid >> 5;                   // 0..7
    const size_t row0 = (size_t)blockIdx.x * PR;
    for (int idx = tid; idx < PR * HH; idx += 256) Hs[idx] = hidden[row0 * HH + idx];
    for (int idx = tid; idx < HH * KK; idx += 256) Dks[idx] = Dk[idx];
    __syncthreads();
    float acc = db[k];
#pragma unroll
    for (int i = 0; i < HH; i += 4) {
        float4 hv = *(const float4*)&Hs[rl * HH + i];
        acc += hv.x * Dks[i * KK + k] + hv.y * Dks[(i + 1) * KK + k]
             + hv.z * Dks[(i + 2) * KK + k] + hv.w * Dks[(i + 3) * KK + k];
    }
    const size_t row = row0 + rl;
    const int t = (int)(row & (TT - 1));
    const int bb = (int)(row >> 10);
    if (t == 0) acc += lb[k];
    if (t == slen[bb] - 1) acc += rb[k];
    pot[row * KK + k] = acc;
}

// ---------------------------------------------------------------------------
// Kernel 5: Viterbi. Forward on wave 0 with 4-deep pot-row prefetch (4
// outstanding loads cover L3/HBM latency); ds_bpermute broadcasts + depth-4
// compare-select tree argmax; bp uint8 in LDS; chunked parallel backtrack.
// ---------------------------------------------------------------------------
__global__ __launch_bounds__(256) void viterbi_kernel(const float* __restrict__ pot,
                                                      const float* __restrict__ chain,
                                                      float* __restrict__ decoded) {
    const int b = blockIdx.x;
    const int tid = threadIdx.x;
    __shared__ unsigned char bp[(TT - 1) * KK];        // 32736 B
    __shared__ unsigned char table[32 * 32 * KK];      // 32 chunks x 32 pos x 32 cand
    __shared__ int ent[32];
    __shared__ int last_tag_s;
    const float* pb = pot + (size_t)b * TT * KK;

    if (tid < 64) {
        const int k = tid & 31;
        const int hf = tid >> 5;                       // half: k_from in [16h,16h+16)
        float ccol[16];
        int addr[16];
#pragma unroll
        for (int m = 0; m < 16; ++m) {
            ccol[m] = chain[(hf * 16 + m) * KK + k];
            addr[m] = (hf * 16 + m) * 4;
        }
        const int addrx = (tid ^ 32) * 4;
        float s = pb[k];
        // 4-deep prefetch ring (reads past pot for b=127 land in slen/chain
        // area of d_out: allocated, values unused)
        float pv0 = pb[1 * KK + k];
        float pv1 = pb[2 * KK + k];
        float pv2 = pb[3 * KK + k];
        float pv3 = pb[4 * KK + k];
        for (int t = 1; t < TT; ++t) {
            float pv = pv0;
            pv0 = pv1; pv1 = pv2; pv2 = pv3;
            pv3 = pb[(size_t)(t + 4) * KK + k];
            const int si = __float_as_int(s);
            float c[16];
#pragma unroll
            for (int m = 0; m < 16; ++m)
                c[m] = __int_as_float(__builtin_amdgcn_ds_bpermute(addr[m], si)) + ccol[m];
            float v1[8]; int i1[8];
#pragma unroll
            for (int p = 0; p < 8; ++p) {
                bool tk = c[2 * p + 1] > c[2 * p];
                v1[p] = tk ? c[2 * p + 1] : c[2 * p];
                i1[p] = hf * 16 + (tk ? 2 * p + 1 : 2 * p);
            }
            float v2[4]; int i2[4];
#pragma unroll
            for (int p = 0; p < 4; ++p) {
                bool tk = v1[2 * p + 1] > v1[2 * p];
                v2[p] = tk ? v1[2 * p + 1] : v1[2 * p];
                i2[p] = tk ? i1[2 * p + 1] : i1[2 * p];
            }
            float v3[2]; int i3[2];
#pragma unroll
            for (int p = 0; p < 2; ++p) {
                bool tk = v2[2 * p + 1] > v2[2 * p];
                v3[p] = tk ? v2[2 * p + 1] : v2[2 * p];
                i3[p] = tk ? i2[2 * p + 1] : i2[2 * p];
            }
            bool tk = v3[1] > v3[0];
            float bv = tk ? v3[1] : v3[0];
            int bi = tk ? i3[1] : i3[0];
            float ov = __int_as_float(__builtin_amdgcn_ds_bpermute(addrx, __float_as_int(bv)));
            int   oi = __builtin_amdgcn_ds_bpermute(addrx, bi);
            bool take = (ov > bv) || (ov == bv && oi < bi);
            if (take) { bv = ov; bi = oi; }
            if (tid < 32) bp[(t - 1) * KK + k] = (unsigned char)bi;
            s = bv + pv;
        }
        float bv = s; int bi = k;
#pragma unroll
        for (int d = 16; d >= 1; d >>= 1) {
            float ov = __shfl_xor(bv, d, 64);
            int   oi = __shfl_xor(bi, d, 64);
            bool take = (ov > bv) || (ov == bv && oi < bi);
            if (take) { bv = ov; bi = oi; }
        }
        if (tid == 0) last_tag_s = bi;
    }
    __syncthreads();
    {
        const int k = tid & 31;
        const int cs = tid >> 5;                       // 0..7
        for (int cc = 0; cc < 4; ++cc) {
            const int c = cs * 4 + cc;
            int tag = k;
            for (int l = 31; l >= 0; --l) {
                const int t = c * 32 + l;
                if (t < TT - 1) tag = bp[t * KK + tag];
                table[(c * 32 + l) * KK + k] = (unsigned char)tag;
            }
        }
    }
    __syncthreads();
    if (tid == 0) {
        int e = last_tag_s;
        ent[31] = e;
        for (int c = 30; c >= 0; --c) { e = table[(c + 1) * 32 * KK + e]; ent[c] = e; }
    }
    __syncthreads();
    for (int t = tid; t < TT; t += 256) {
        const int c = t >> 5, l = t & 31;
        decoded[(size_t)b * TT + t] = (float)table[(c * 32 + l) * KK + ent[c]];
    }
}

// ---------------------------------------------------------------------------
extern "C" void kernel_launch(void* const* d_in, const int* in_sizes, int n_in,
                              void* d_out, int out_size, void* d_ws, size_t ws_size,
                              hipStream_t stream) {
    const float* X     = (const float*)d_in[0];
    const int*   mask  = (const int*)d_in[1];
    const float* Wk    = (const float*)d_in[2];   // [128,192]
    const float* Wr    = (const float*)d_in[3];   // [64,192]
    const float* gb    = (const float*)d_in[4];   // [2,192]
    const float* Dk    = (const float*)d_in[5];   // [64,32]
    const float* db    = (const float*)d_in[6];   // [32]
    const float* chain = (const float*)d_in[7];   // [32,32]
    const float* lb    = (const float*)d_in[8];
    const float* rb    = (const float*)d_in[9];

    float* out = (float*)d_out;
    float* out_dec  = out;                                   // [B,T]
    float* out_pot  = out + (size_t)BB * TT;                 // [B,T,K]
    float* out_slen = out + (size_t)BB * TT + (size_t)BB * TT * KK;        // [B]
    float* out_chn  = out_slen + BB;                         // [K,K]

    float* ws = (float*)d_ws;
    float* xp     = ws;                                      // [B*T,192]
    float* hidden = ws + (size_t)BB * TT * G3;               // [B*T,64]
    int*   slen_i = (int*)(hidden + (size_t)BB * TT * HH);   // [B]

    xproj_kernel<<<dim3((BB * TT) / 64, 3), dim3(256), 0, stream>>>(X, Wk, gb, xp);
    seqlen_kernel<<<dim3(BB), dim3(256), 0, stream>>>(mask, chain, out_slen, out_chn, slen_i);
    gru_kernel<<<dim3(BB), dim3(192), 0, stream>>>(xp, Wr, gb, mask, hidden);
    pot_kernel<<<dim3((BB * TT) / PR), dim3(256), 0, stream>>>(hidden, Dk, db, lb, rb, slen_i, out_pot);
    viterbi_kernel<<<dim3(BB), dim3(256), 0, stream>>>(out_pot, chain, out_dec);
}